// Round 1
// baseline (610.636 us; speedup 1.0000x reference)
//
#include <hip/hip_runtime.h>

namespace {

constexpr int kNS   = 128;
constexpr int kNV   = 64;
constexpr int kFC   = 64;
constexpr int kWN   = 448;   // 2*NS + 3*NV
constexpr int kSROW = 192;   // NS + NV
constexpr int kVOUT = 64;
constexpr int kNodeW = kNS + 3 * kNV;   // 320
constexpr int kOutW  = kNS + 3 * kVOUT; // 320

constexpr int EPW   = 4;   // edges per wave (weight-load amortization)
constexpr int WAVES = 4;   // waves per block
constexpr int EPB   = EPW * WAVES;

__device__ __forceinline__ float bl(float v, int l) {
  // wave-uniform broadcast of lane l's value via v_readlane (no LDS pipe)
  return __int_as_float(__builtin_amdgcn_readlane(__float_as_int(v), l));
}
__device__ __forceinline__ float frcp(float x) { return __builtin_amdgcn_rcpf(x); }
__device__ __forceinline__ float fsilu(float x) { return x * frcp(1.0f + __expf(-x)); }
__device__ __forceinline__ float fsig(float x) { return frcp(1.0f + __expf(-x)); }

__global__ __launch_bounds__(WAVES * 64) void fctp_fused(
    const float* __restrict__ node_input, const float* __restrict__ edge_attr,
    const float* __restrict__ edge_scalars,
    const float* __restrict__ W1, const float* __restrict__ b1,
    const float* __restrict__ W2, const float* __restrict__ b2,
    const float* __restrict__ W3, const float* __restrict__ offset,
    const float* __restrict__ Ws, const float* __restrict__ bs,
    const float* __restrict__ Wv, const float* __restrict__ g_s,
    const float* __restrict__ b_n, const float* __restrict__ g_v,
    float* __restrict__ out, int E) {
  const int lane  = threadIdx.x & 63;
  const int wave  = threadIdx.x >> 6;
  const int ebase = (int)blockIdx.x * EPB + wave * EPW;
  if (ebase >= E) return;

  int eidx[EPW];
#pragma unroll
  for (int t = 0; t < EPW; ++t) {
    int e = ebase + t;
    eidx[t] = (e < E) ? e : (E - 1);
  }

  // ---------------- MLP: h = silu(silu(es@W1+b1)@W2+b2) ----------------
  float h[EPW], acc[EPW];
  {
    float es[EPW];
#pragma unroll
    for (int t = 0; t < EPW; ++t)
      es[t] = edge_scalars[(size_t)eidx[t] * kFC + lane];
    float bv = b1[lane];
#pragma unroll
    for (int t = 0; t < EPW; ++t) acc[t] = bv;
    for (int k = 0; k < kFC; ++k) {
      float wv = W1[k * kFC + lane];
#pragma unroll
      for (int t = 0; t < EPW; ++t) acc[t] += bl(es[t], k) * wv;
    }
#pragma unroll
    for (int t = 0; t < EPW; ++t) h[t] = fsilu(acc[t]);
    bv = b2[lane];
#pragma unroll
    for (int t = 0; t < EPW; ++t) acc[t] = bv;
    for (int k = 0; k < kFC; ++k) {
      float wv = W2[k * kFC + lane];
#pragma unroll
      for (int t = 0; t < EPW; ++t) acc[t] += bl(h[t], k) * wv;
    }
#pragma unroll
    for (int t = 0; t < EPW; ++t) h[t] = fsilu(acc[t]);
  }

  // ---------------- w = h @ W3 + offset  (448 cols -> 7 per lane) ------
  // tt: 0->w1[l], 1->w1[64+l], 2->w2[l], 3->w2[64+l], 4->w3[l], 5->w4[l], 6->w5[l]
  float wc[EPW][7];
#pragma unroll
  for (int tt = 0; tt < 7; ++tt) {
    float ov = offset[tt * 64 + lane];
#pragma unroll
    for (int t = 0; t < EPW; ++t) wc[t][tt] = ov;
  }
  for (int k = 0; k < kFC; ++k) {
    float hv[EPW];
#pragma unroll
    for (int t = 0; t < EPW; ++t) hv[t] = bl(h[t], k);
    const float* wr = W3 + (size_t)k * kWN + lane;
#pragma unroll
    for (int tt = 0; tt < 7; ++tt) {
      float wv = wr[tt * 64];
#pragma unroll
      for (int t = 0; t < EPW; ++t) wc[t][tt] += hv[t] * wv;
    }
  }

  // ---------------- node / edge-attr loads ----------------
  float sa[EPW], sb[EPW], vx[EPW], vy[EPW], vz[EPW];
  float E0[EPW], E1x[EPW], E1y[EPW], E1z[EPW];
#pragma unroll
  for (int t = 0; t < EPW; ++t) {
    const float* ni = node_input + (size_t)eidx[t] * kNodeW;
    sa[t] = ni[lane];
    sb[t] = ni[64 + lane];
    vx[t] = ni[kNS + lane * 3 + 0];
    vy[t] = ni[kNS + lane * 3 + 1];
    vz[t] = ni[kNS + lane * 3 + 2];
    const float* ea = edge_attr + (size_t)eidx[t] * 4;
    E0[t]  = ea[0];
    E1x[t] = ea[1];
    E1y[t] = ea[2];
    E1z[t] = ea[3];
  }

  const float RS3 = 0.5773502691896258f;  // 1/sqrt(3)
  const float RS2 = 0.7071067811865476f;  // 1/sqrt(2)

  // ---------------- tensor products (register-resident) ----------------
  // scal = [o0a(128), o0b(64)], p = w2*s (o1a factor), q = w3*v, r = w5*cross(v,e1)
  float sc0[EPW], sc1[EPW], sc2[EPW];
  float p0[EPW], p1[EPW];
  float qx[EPW], qy[EPW], qz[EPW], rx[EPW], ry[EPW], rz[EPW];
#pragma unroll
  for (int t = 0; t < EPW; ++t) {
    sc0[t] = E0[t] * wc[t][0] * sa[t];
    sc1[t] = E0[t] * wc[t][1] * sb[t];
    float dot = vx[t] * E1x[t] + vy[t] * E1y[t] + vz[t] * E1z[t];
    sc2[t] = wc[t][5] * dot * RS3;
    p0[t] = wc[t][2] * sa[t];
    p1[t] = wc[t][3] * sb[t];
    qx[t] = wc[t][4] * vx[t];
    qy[t] = wc[t][4] * vy[t];
    qz[t] = wc[t][4] * vz[t];
    float cx = vy[t] * E1z[t] - vz[t] * E1y[t];
    float cy = vz[t] * E1x[t] - vx[t] * E1z[t];
    float cz = vx[t] * E1y[t] - vy[t] * E1x[t];
    rx[t] = wc[t][6] * cx;
    ry[t] = wc[t][6] * cy;
    rz[t] = wc[t][6] * cz;
  }

  // ---------------- s_lin = scal @ Ws + bs  (192 cols -> 3 per lane) ----
  float sl0[EPW], sl1[EPW], sl2[EPW];
  {
    float bv0 = bs[lane], bv1 = bs[64 + lane], bv2 = bs[128 + lane];
#pragma unroll
    for (int t = 0; t < EPW; ++t) { sl0[t] = bv0; sl1[t] = bv1; sl2[t] = bv2; }
  }
  auto ws_block = [&](const float (&src)[EPW], int ubase) {
    for (int k = 0; k < 64; ++k) {
      const float* wr = Ws + (size_t)(ubase + k) * kSROW + lane;
      float w0 = wr[0], wA = wr[64], wB = wr[128];
      float sv[EPW];
#pragma unroll
      for (int t = 0; t < EPW; ++t) sv[t] = bl(src[t], k);
#pragma unroll
      for (int t = 0; t < EPW; ++t) {
        sl0[t] += sv[t] * w0;
        sl1[t] += sv[t] * wA;
        sl2[t] += sv[t] * wB;
      }
    }
  };
  ws_block(sc0, 0);
  ws_block(sc1, 64);
  ws_block(sc2, 128);

  // ---------------- v_lin (factorized):
  // v_lin[o][c] = e1[c]*pacc[o] + e0*qacc_c[o] + (1/sqrt2)*racc_c[o]
  float pa[EPW];
  float qax[EPW], qay[EPW], qaz[EPW], rax[EPW], ray[EPW], raz[EPW];
#pragma unroll
  for (int t = 0; t < EPW; ++t) {
    pa[t] = 0.f;
    qax[t] = qay[t] = qaz[t] = 0.f;
    rax[t] = ray[t] = raz[t] = 0.f;
  }
  auto wv_p = [&](const float (&src)[EPW], int ubase) {
    for (int k = 0; k < 64; ++k) {
      float wv = Wv[(size_t)(ubase + k) * kVOUT + lane];
      float sv[EPW];
#pragma unroll
      for (int t = 0; t < EPW; ++t) sv[t] = bl(src[t], k);
#pragma unroll
      for (int t = 0; t < EPW; ++t) pa[t] += sv[t] * wv;
    }
  };
  wv_p(p0, 0);
  wv_p(p1, 64);
  for (int m = 0; m < 64; ++m) {
    float wv = Wv[(size_t)(128 + m) * kVOUT + lane];
#pragma unroll
    for (int t = 0; t < EPW; ++t) {
      qax[t] += bl(qx[t], m) * wv;
      qay[t] += bl(qy[t], m) * wv;
      qaz[t] += bl(qz[t], m) * wv;
    }
  }
  for (int m = 0; m < 64; ++m) {
    float wv = Wv[(size_t)(192 + m) * kVOUT + lane];
#pragma unroll
    for (int t = 0; t < EPW; ++t) {
      rax[t] += bl(rx[t], m) * wv;
      ray[t] += bl(ry[t], m) * wv;
      raz[t] += bl(rz[t], m) * wv;
    }
  }

  // ---------------- norms + gating + store ----------------
  float gs0 = g_s[lane], gs1 = g_s[64 + lane], gs2 = g_s[128 + lane];
  float bn0 = b_n[lane], bn1 = b_n[64 + lane], bn2 = b_n[128 + lane];
  float gvv = g_v[lane];

#pragma unroll
  for (int t = 0; t < EPW; ++t) {
    float vlx = pa[t] * E1x[t] + E0[t] * qax[t] + rax[t] * RS2;
    float vly = pa[t] * E1y[t] + E0[t] * qay[t] + ray[t] * RS2;
    float vlz = pa[t] * E1z[t] + E0[t] * qaz[t] + raz[t] * RS2;

    float sx  = sl0[t] + sl1[t] + sl2[t];
    float sxx = sl0[t] * sl0[t] + sl1[t] * sl1[t] + sl2[t] * sl2[t];
    float vsq = vlx * vlx + vly * vly + vlz * vlz;
#pragma unroll
    for (int m = 32; m >= 1; m >>= 1) {
      sx  += __shfl_xor(sx, m);
      sxx += __shfl_xor(sxx, m);
      vsq += __shfl_xor(vsq, m);
    }
    float mean = sx * (1.0f / 192.0f);
    float var  = sxx * (1.0f / 192.0f) - mean * mean;
    float rstd = __builtin_amdgcn_rsqf(var + 1e-5f);
    float vn   = __builtin_amdgcn_rsqf(vsq * (1.0f / 64.0f) + 1e-5f);

    float sn0 = gs0 * (sl0[t] - mean) * rstd + bn0;
    float sn1 = gs1 * (sl1[t] - mean) * rstd + bn1;
    float sn2 = gs2 * (sl2[t] - mean) * rstd + bn2;
    float gate = fsig(sn2);

    if (ebase + t < E) {
      float* o = out + (size_t)(ebase + t) * kOutW;
      o[lane]      = fsilu(sn0);
      o[64 + lane] = fsilu(sn1);
      float m3 = gvv * vn * gate;
      o[kNS + lane * 3 + 0] = m3 * vlx;
      o[kNS + lane * 3 + 1] = m3 * vly;
      o[kNS + lane * 3 + 2] = m3 * vlz;
    }
  }
}

}  // namespace

extern "C" void kernel_launch(void* const* d_in, const int* in_sizes, int n_in,
                              void* d_out, int out_size, void* d_ws, size_t ws_size,
                              hipStream_t stream) {
  const float* node_input   = (const float*)d_in[0];
  const float* edge_attr    = (const float*)d_in[1];
  const float* edge_scalars = (const float*)d_in[2];
  const float* W1 = (const float*)d_in[3];
  const float* b1 = (const float*)d_in[4];
  const float* W2 = (const float*)d_in[5];
  const float* b2 = (const float*)d_in[6];
  const float* W3 = (const float*)d_in[7];
  const float* offset = (const float*)d_in[8];
  const float* Ws = (const float*)d_in[9];
  const float* bs = (const float*)d_in[10];
  const float* Wv = (const float*)d_in[11];
  const float* g_s = (const float*)d_in[12];
  const float* b_n = (const float*)d_in[13];
  const float* g_v = (const float*)d_in[14];
  float* out = (float*)d_out;

  const int E = in_sizes[0] / kNodeW;
  const int grid = (E + EPB - 1) / EPB;
  fctp_fused<<<grid, WAVES * 64, 0, stream>>>(
      node_input, edge_attr, edge_scalars, W1, b1, W2, b2, W3, offset, Ws, bs,
      Wv, g_s, b_n, g_v, out, E);
}

// Round 2
// 438.432 us; speedup vs baseline: 1.3928x; 1.3928x over previous
//
#include <hip/hip_runtime.h>

typedef short short8 __attribute__((ext_vector_type(8)));
typedef __bf16 bf16x8 __attribute__((ext_vector_type(8)));
typedef float f32x4 __attribute__((ext_vector_type(4)));

namespace {

constexpr int kNodeW = 320;   // NS + 3*NV
constexpr int kOutW  = 320;   // NS + 3*VOUT
constexpr int ET     = 32;    // edges per block (2 waves x 16)

// packed B-fragment bases (units of 1 frag = 64 lanes * 8 ushort = 512 ushort)
constexpr int F_W1 = 0;    // 2 kb * 4 nt
constexpr int F_W2 = 8;
constexpr int F_W3 = 16;   // 2 kb * 28 nt
constexpr int F_WS = 72;   // 6 kb * 12 nt
constexpr int F_WP = 144;  // 4 kb * 4 nt   (Wv rows 0..127)
constexpr int F_WQ = 160;  // 2 kb * 4 nt   (Wv rows 128..191)
constexpr int F_WR = 168;  // 2 kb * 4 nt   (Wv rows 192..255)
constexpr int NFRAG = 176; // 176 KB in d_ws

// LDS tiles (bf16, XOR-swizzled rows)
constexpr int SB_ACT = 128, SB_SCAL = 384, SB_P = 256, SB_Q = 128;
constexpr int O_ACT = 0;            // [32][64]
constexpr int O_SCAL = 4096;        // [32][192]
constexpr int O_P = 16384;          // [32][128]
constexpr int O_Q0 = 24576, O_Q1 = 28672, O_Q2 = 32768;   // [32][64] each
constexpr int O_R0 = 36864, O_R1 = 40960, O_R2 = 45056;
constexpr int SMEM_SZ = 49152;

constexpr float RS3 = 0.5773502691896258f;  // 1/sqrt(3)
constexpr float RS2 = 0.7071067811865476f;  // 1/sqrt(2)

__device__ __forceinline__ ushort f2b(float f) {
  uint x = __float_as_uint(f);
  return (ushort)((x + 0x7FFFu + ((x >> 16) & 1u)) >> 16);  // RNE
}
__device__ __forceinline__ float fsig(float x) { return 1.0f / (1.0f + __expf(-x)); }
__device__ __forceinline__ float fsilu(float x) { return x / (1.0f + __expf(-x)); }

__device__ __forceinline__ f32x4 MFMA(short8 a, short8 b, f32x4 c) {
  return __builtin_amdgcn_mfma_f32_16x16x32_bf16(
      __builtin_bit_cast(bf16x8, a), __builtin_bit_cast(bf16x8, b), c, 0, 0, 0);
}

// swizzled LDS helpers: byte ^= (row&7)<<4 (spreads the 128B-aligned row stride)
__device__ __forceinline__ void lwr16(char* smem, int tile, int SB, int row, int col, ushort v) {
  *(ushort*)(smem + tile + (((row * SB) + col * 2) ^ ((row & 7) << 4))) = v;
}
__device__ __forceinline__ short8 lra(const char* smem, int tile, int SB, int row, int kb, int lg) {
  int off = row * SB + kb * 64 + lg * 16;  // 8 consecutive bf16 at k0 = kb*32 + lg*8
  return *(const short8*)(smem + tile + (off ^ ((row & 7) << 4)));
}

// ---------------- B pack: f32 [K][N] -> bf16 frag layout in d_ws ----------------
__global__ void pack_weights(const float* __restrict__ W1, const float* __restrict__ W2,
                             const float* __restrict__ W3, const float* __restrict__ Ws,
                             const float* __restrict__ Wv, ushort* __restrict__ dst) {
  int f = blockIdx.x, lane = threadIdx.x;
  const float* src; int ldw, kbase, NT, local;
  if (f < 8)        { src = W1; ldw = 64;  kbase = 0;   NT = 4;  local = f; }
  else if (f < 16)  { src = W2; ldw = 64;  kbase = 0;   NT = 4;  local = f - 8; }
  else if (f < 72)  { src = W3; ldw = 448; kbase = 0;   NT = 28; local = f - 16; }
  else if (f < 144) { src = Ws; ldw = 192; kbase = 0;   NT = 12; local = f - 72; }
  else if (f < 160) { src = Wv; ldw = 64;  kbase = 0;   NT = 4;  local = f - 144; }
  else if (f < 168) { src = Wv; ldw = 64;  kbase = 128; NT = 4;  local = f - 160; }
  else              { src = Wv; ldw = 64;  kbase = 192; NT = 4;  local = f - 168; }
  int kb = local / NT, nt = local % NT;
  int k0  = kbase + kb * 32 + (lane >> 4) * 8;
  int col = nt * 16 + (lane & 15);
  ushort* o = dst + ((size_t)f * 64 + lane) * 8;
#pragma unroll
  for (int j = 0; j < 8; ++j) o[j] = f2b(src[(size_t)(k0 + j) * ldw + col]);
}

// ---------------- main fused kernel ----------------
__global__ __launch_bounds__(128) void fctp_main(
    const float* __restrict__ node, const float* __restrict__ eattr,
    const float* __restrict__ es, const float* __restrict__ b1,
    const float* __restrict__ b2, const float* __restrict__ offs,
    const float* __restrict__ bs, const float* __restrict__ g_s,
    const float* __restrict__ b_n, const float* __restrict__ g_v,
    const short8* __restrict__ wsv, float* __restrict__ out, int E) {
  __shared__ __align__(16) char smem[SMEM_SZ];
  const int lane = threadIdx.x & 63;
  const int wave = threadIdx.x >> 6;
  const int l15 = lane & 15, lg = lane >> 4;
  const int ebW = (int)blockIdx.x * ET + wave * 16;  // wave's first edge
  const int rowA = wave * 16 + l15;                  // A-frag LDS row
  int geA = ebW + l15; if (geA >= E) geA = E - 1;    // A-frag edge (clamped)

  const f32x4 ZV = {0.f, 0.f, 0.f, 0.f};

  // ---- stage 1: h1 = silu(es @ W1 + b1), write to act LDS ----
  {
    f32x4 acc[4];
#pragma unroll
    for (int nt = 0; nt < 4; ++nt) { float bv = b1[nt * 16 + l15]; acc[nt] = (f32x4){bv, bv, bv, bv}; }
#pragma unroll
    for (int kb = 0; kb < 2; ++kb) {
      const float* p = es + (size_t)geA * 64 + kb * 32 + lg * 8;
      float4 xa = *(const float4*)p;
      float4 xb = *(const float4*)(p + 4);
      short8 a;
      a[0] = (short)f2b(xa.x); a[1] = (short)f2b(xa.y); a[2] = (short)f2b(xa.z); a[3] = (short)f2b(xa.w);
      a[4] = (short)f2b(xb.x); a[5] = (short)f2b(xb.y); a[6] = (short)f2b(xb.z); a[7] = (short)f2b(xb.w);
#pragma unroll
      for (int nt = 0; nt < 4; ++nt)
        acc[nt] = MFMA(a, wsv[(F_W1 + kb * 4 + nt) * 64 + lane], acc[nt]);
    }
#pragma unroll
    for (int nt = 0; nt < 4; ++nt)
#pragma unroll
      for (int r = 0; r < 4; ++r) {
        int row = wave * 16 + lg * 4 + r;
        lwr16(smem, O_ACT, SB_ACT, row, nt * 16 + l15, f2b(fsilu(acc[nt][r])));
      }
  }

  // ---- stage 2: h2 = silu(h1 @ W2 + b2) (reads then overwrites act) ----
  {
    f32x4 acc[4];
#pragma unroll
    for (int nt = 0; nt < 4; ++nt) { float bv = b2[nt * 16 + l15]; acc[nt] = (f32x4){bv, bv, bv, bv}; }
    short8 a0 = lra(smem, O_ACT, SB_ACT, rowA, 0, lg);
    short8 a1 = lra(smem, O_ACT, SB_ACT, rowA, 1, lg);
#pragma unroll
    for (int nt = 0; nt < 4; ++nt) acc[nt] = MFMA(a0, wsv[(F_W2 + nt) * 64 + lane], acc[nt]);
#pragma unroll
    for (int nt = 0; nt < 4; ++nt) acc[nt] = MFMA(a1, wsv[(F_W2 + 4 + nt) * 64 + lane], acc[nt]);
#pragma unroll
    for (int nt = 0; nt < 4; ++nt)
#pragma unroll
      for (int r = 0; r < 4; ++r) {
        int row = wave * 16 + lg * 4 + r;
        lwr16(smem, O_ACT, SB_ACT, row, nt * 16 + l15, f2b(fsilu(acc[nt][r])));
      }
  }

  // ---- stage 3: w = h2 @ W3 + offset (28 col-tiles, kept in regs) ----
  f32x4 wacc[28];
#pragma unroll
  for (int nt = 0; nt < 28; ++nt) { float bv = offs[nt * 16 + l15]; wacc[nt] = (f32x4){bv, bv, bv, bv}; }
  {
    short8 a0 = lra(smem, O_ACT, SB_ACT, rowA, 0, lg);
    short8 a1 = lra(smem, O_ACT, SB_ACT, rowA, 1, lg);
#pragma unroll
    for (int nt = 0; nt < 28; ++nt) wacc[nt] = MFMA(a0, wsv[(F_W3 + nt) * 64 + lane], wacc[nt]);
#pragma unroll
    for (int nt = 0; nt < 28; ++nt) wacc[nt] = MFMA(a1, wsv[(F_W3 + 28 + nt) * 64 + lane], wacc[nt]);
  }

  // ---- edge attrs for this lane's 4 C-rows ----
  float e0s[4], e1xs[4], e1ys[4], e1zs[4];
#pragma unroll
  for (int r = 0; r < 4; ++r) {
    int ge = ebW + lg * 4 + r; if (ge >= E) ge = E - 1;
    const float* ea = eattr + (size_t)ge * 4;
    e0s[r] = ea[0]; e1xs[r] = ea[1]; e1ys[r] = ea[2]; e1zs[r] = ea[3];
  }

  // ---- tensor product in C-frag layout -> scal/p/q/r LDS (bf16) ----
#pragma unroll
  for (int r = 0; r < 4; ++r) {
    int ge = ebW + lg * 4 + r; if (ge >= E) ge = E - 1;
    int row = wave * 16 + lg * 4 + r;
    const float* ni = node + (size_t)ge * kNodeW;
    // scalar-driven channels: w1 (cols 0..127) -> scal, w2 (128..255) -> p
#pragma unroll
    for (int nt = 0; nt < 16; ++nt) {
      int c = nt * 16 + l15;
      float s = ni[c & 127];
      float w = wacc[nt][r];
      if (nt < 8) lwr16(smem, O_SCAL, SB_SCAL, row, c, f2b(e0s[r] * w * s));
      else        lwr16(smem, O_P, SB_P, row, c - 128, f2b(w * s));
    }
    // vector-driven channels: w3 (q), w4 (sc2), w5 (r-cross)
#pragma unroll
    for (int nt = 0; nt < 4; ++nt) {
      int u = nt * 16 + l15;
      float vx = ni[128 + 3 * u], vy = ni[129 + 3 * u], vz = ni[130 + 3 * u];
      float wq = wacc[16 + nt][r], w4 = wacc[20 + nt][r], w5 = wacc[24 + nt][r];
      lwr16(smem, O_Q0, SB_Q, row, u, f2b(wq * vx));
      lwr16(smem, O_Q1, SB_Q, row, u, f2b(wq * vy));
      lwr16(smem, O_Q2, SB_Q, row, u, f2b(wq * vz));
      float dot = vx * e1xs[r] + vy * e1ys[r] + vz * e1zs[r];
      lwr16(smem, O_SCAL, SB_SCAL, row, 128 + u, f2b(w4 * dot * RS3));
      float cx = vy * e1zs[r] - vz * e1ys[r];
      float cy = vz * e1xs[r] - vx * e1zs[r];
      float cz = vx * e1ys[r] - vy * e1xs[r];
      lwr16(smem, O_R0, SB_Q, row, u, f2b(w5 * cx * RS2));
      lwr16(smem, O_R1, SB_Q, row, u, f2b(w5 * cy * RS2));
      lwr16(smem, O_R2, SB_Q, row, u, f2b(w5 * cz * RS2));
    }
  }

  // ---- stage 5: s_lin = scal @ Ws + bs ----
  f32x4 sacc[12];
#pragma unroll
  for (int nt = 0; nt < 12; ++nt) { float bv = bs[nt * 16 + l15]; sacc[nt] = (f32x4){bv, bv, bv, bv}; }
#pragma unroll
  for (int kb = 0; kb < 6; ++kb) {
    short8 a = lra(smem, O_SCAL, SB_SCAL, rowA, kb, lg);
#pragma unroll
    for (int nt = 0; nt < 12; ++nt)
      sacc[nt] = MFMA(a, wsv[(F_WS + kb * 12 + nt) * 64 + lane], sacc[nt]);
  }

  // ---- layernorm + silu/gate split ----
  float gate[4][4];
  {
    float gsv[12], bnv[12];
#pragma unroll
    for (int nt = 0; nt < 12; ++nt) { gsv[nt] = g_s[nt * 16 + l15]; bnv[nt] = b_n[nt * 16 + l15]; }
#pragma unroll
    for (int r = 0; r < 4; ++r) {
      float sx = 0.f, sxx = 0.f;
#pragma unroll
      for (int nt = 0; nt < 12; ++nt) { float v = sacc[nt][r]; sx += v; sxx += v * v; }
#pragma unroll
      for (int m = 8; m >= 1; m >>= 1) { sx += __shfl_xor(sx, m); sxx += __shfl_xor(sxx, m); }
      float mean = sx * (1.0f / 192.0f);
      float var = sxx * (1.0f / 192.0f) - mean * mean;
      float rstd = rsqrtf(var + 1e-5f);
      int ge = ebW + lg * 4 + r;
      bool valid = ge < E;
      float* ob = out + (size_t)(valid ? ge : 0) * kOutW;
#pragma unroll
      for (int nt = 0; nt < 12; ++nt) {
        float sn = gsv[nt] * (sacc[nt][r] - mean) * rstd + bnv[nt];
        if (nt < 8) { if (valid) ob[nt * 16 + l15] = fsilu(sn); }
        else gate[r][nt - 8] = fsig(sn);
      }
    }
  }

  // ---- stage 6: v GEMMs (pa, q_c, r_c) ----
  f32x4 pacc[4], qacc[3][4], racc[3][4];
#pragma unroll
  for (int nt = 0; nt < 4; ++nt) {
    pacc[nt] = ZV;
#pragma unroll
    for (int c = 0; c < 3; ++c) { qacc[c][nt] = ZV; racc[c][nt] = ZV; }
  }
#pragma unroll
  for (int kb = 0; kb < 4; ++kb) {
    short8 a = lra(smem, O_P, SB_P, rowA, kb, lg);
#pragma unroll
    for (int nt = 0; nt < 4; ++nt)
      pacc[nt] = MFMA(a, wsv[(F_WP + kb * 4 + nt) * 64 + lane], pacc[nt]);
  }
#pragma unroll
  for (int kb = 0; kb < 2; ++kb) {
    short8 aq0 = lra(smem, O_Q0, SB_Q, rowA, kb, lg);
    short8 aq1 = lra(smem, O_Q1, SB_Q, rowA, kb, lg);
    short8 aq2 = lra(smem, O_Q2, SB_Q, rowA, kb, lg);
#pragma unroll
    for (int nt = 0; nt < 4; ++nt) {
      short8 b = wsv[(F_WQ + kb * 4 + nt) * 64 + lane];
      qacc[0][nt] = MFMA(aq0, b, qacc[0][nt]);
      qacc[1][nt] = MFMA(aq1, b, qacc[1][nt]);
      qacc[2][nt] = MFMA(aq2, b, qacc[2][nt]);
    }
  }
#pragma unroll
  for (int kb = 0; kb < 2; ++kb) {
    short8 ar0 = lra(smem, O_R0, SB_Q, rowA, kb, lg);
    short8 ar1 = lra(smem, O_R1, SB_Q, rowA, kb, lg);
    short8 ar2 = lra(smem, O_R2, SB_Q, rowA, kb, lg);
#pragma unroll
    for (int nt = 0; nt < 4; ++nt) {
      short8 b = wsv[(F_WR + kb * 4 + nt) * 64 + lane];
      racc[0][nt] = MFMA(ar0, b, racc[0][nt]);
      racc[1][nt] = MFMA(ar1, b, racc[1][nt]);
      racc[2][nt] = MFMA(ar2, b, racc[2][nt]);
    }
  }

  // ---- v epilogue: combine, RMS-norm, gate, store ----
  {
    float gvv[4];
#pragma unroll
    for (int nt = 0; nt < 4; ++nt) gvv[nt] = g_v[nt * 16 + l15];
#pragma unroll
    for (int r = 0; r < 4; ++r) {
      float vlx[4], vly[4], vlz[4];
      float vsq = 0.f;
#pragma unroll
      for (int nt = 0; nt < 4; ++nt) {
        vlx[nt] = pacc[nt][r] * e1xs[r] + e0s[r] * qacc[0][nt][r] + racc[0][nt][r];
        vly[nt] = pacc[nt][r] * e1ys[r] + e0s[r] * qacc[1][nt][r] + racc[1][nt][r];
        vlz[nt] = pacc[nt][r] * e1zs[r] + e0s[r] * qacc[2][nt][r] + racc[2][nt][r];
        vsq += vlx[nt] * vlx[nt] + vly[nt] * vly[nt] + vlz[nt] * vlz[nt];
      }
#pragma unroll
      for (int m = 8; m >= 1; m >>= 1) vsq += __shfl_xor(vsq, m);
      float vn = rsqrtf(vsq * (1.0f / 64.0f) + 1e-5f);
      int ge = ebW + lg * 4 + r;
      if (ge < E) {
        float* ob = out + (size_t)ge * kOutW + 128;
#pragma unroll
        for (int nt = 0; nt < 4; ++nt) {
          float m3 = gvv[nt] * vn * gate[r][nt];
          int o3 = (nt * 16 + l15) * 3;
          ob[o3 + 0] = m3 * vlx[nt];
          ob[o3 + 1] = m3 * vly[nt];
          ob[o3 + 2] = m3 * vlz[nt];
        }
      }
    }
  }
}

}  // namespace

extern "C" void kernel_launch(void* const* d_in, const int* in_sizes, int n_in,
                              void* d_out, int out_size, void* d_ws, size_t ws_size,
                              hipStream_t stream) {
  const float* node_input   = (const float*)d_in[0];
  const float* edge_attr    = (const float*)d_in[1];
  const float* edge_scalars = (const float*)d_in[2];
  const float* W1 = (const float*)d_in[3];
  const float* b1 = (const float*)d_in[4];
  const float* W2 = (const float*)d_in[5];
  const float* b2 = (const float*)d_in[6];
  const float* W3 = (const float*)d_in[7];
  const float* offset = (const float*)d_in[8];
  const float* Ws = (const float*)d_in[9];
  const float* bs = (const float*)d_in[10];
  const float* Wv = (const float*)d_in[11];
  const float* g_s = (const float*)d_in[12];
  const float* b_n = (const float*)d_in[13];
  const float* g_v = (const float*)d_in[14];
  float* out = (float*)d_out;

  const int E = in_sizes[0] / kNodeW;

  pack_weights<<<NFRAG, 64, 0, stream>>>(W1, W2, W3, Ws, Wv, (ushort*)d_ws);

  const int blocks = (E + ET - 1) / ET;
  fctp_main<<<blocks, 128, 0, stream>>>(
      node_input, edge_attr, edge_scalars, b1, b2, offset, bs, g_s, b_n, g_v,
      (const short8*)d_ws, out, E);
}

// Round 3
// 400.924 us; speedup vs baseline: 1.5231x; 1.0936x over previous
//
#include <hip/hip_runtime.h>

typedef short short8 __attribute__((ext_vector_type(8)));
typedef __bf16 bf16x8 __attribute__((ext_vector_type(8)));
typedef float f32x4 __attribute__((ext_vector_type(4)));

namespace {

constexpr int kNodeW = 320;   // NS + 3*NV
constexpr int kOutW  = 320;   // NS + 3*VOUT
constexpr int EPW    = 32;    // edges per wave = 2 MFMA tiles
constexpr int WAVES  = 4;
constexpr int EPB    = EPW * WAVES;  // 128

// packed B-fragment bases (1 frag = 64 lanes * 8 ushort)
constexpr int F_W1 = 0;    // 2kb * 4nt
constexpr int F_W2 = 8;
constexpr int F_W3 = 16;   // kb*28 + nt (kb 0..1, nt 0..27)
constexpr int F_WS = 72;   // kb*12 + nt (kb 0..5)
constexpr int F_WP = 144;  // kb*4 + nt (kb 0..3)  Wv rows 0..127
constexpr int F_WQ = 160;  // kb*4 + nt (kb 0..1)  Wv rows 128..191
constexpr int F_WR = 168;  // kb*4 + nt (kb 0..1)  Wv rows 192..255
constexpr int NFRAG = 176;

constexpr float RS3 = 0.5773502691896258f;  // 1/sqrt(3)
constexpr float RS2 = 0.7071067811865476f;  // 1/sqrt(2)

__device__ __forceinline__ ushort f2b(float f) {
  uint x = __float_as_uint(f);
  return (ushort)((x + 0x7FFFu + ((x >> 16) & 1u)) >> 16);  // RNE
}
__device__ __forceinline__ float fsig(float x) { return 1.0f / (1.0f + __expf(-x)); }
__device__ __forceinline__ float fsilu(float x) { return x / (1.0f + __expf(-x)); }
__device__ __forceinline__ f32x4 MFMA(short8 a, short8 b, f32x4 c) {
  return __builtin_amdgcn_mfma_f32_16x16x32_bf16(
      __builtin_bit_cast(bf16x8, a), __builtin_bit_cast(bf16x8, b), c, 0, 0, 0);
}

// chunk arena: 32 rows x 64 bf16 cols, row stride 128B, XOR swizzle vs 32-way conflicts
__device__ __forceinline__ void cw16(char* ar, int row, int col, ushort v) {
  *(ushort*)(ar + ((row * 128 + col * 2) ^ ((row & 7) << 4))) = v;
}
__device__ __forceinline__ short8 cra(const char* ar, int row, int kb, int lg) {
  return *(const short8*)(ar + ((row * 128 + kb * 64 + lg * 16) ^ ((row & 7) << 4)));
}

// ---------------- B pack: f32 [K][N] -> bf16 frag layout in d_ws ----------------
__global__ void pack_weights(const float* __restrict__ W1, const float* __restrict__ W2,
                             const float* __restrict__ W3, const float* __restrict__ Ws,
                             const float* __restrict__ Wv, ushort* __restrict__ dst) {
  int f = blockIdx.x, lane = threadIdx.x;
  const float* src; int ldw, kbase, NT, local;
  if (f < 8)        { src = W1; ldw = 64;  kbase = 0;   NT = 4;  local = f; }
  else if (f < 16)  { src = W2; ldw = 64;  kbase = 0;   NT = 4;  local = f - 8; }
  else if (f < 72)  { src = W3; ldw = 448; kbase = 0;   NT = 28; local = f - 16; }
  else if (f < 144) { src = Ws; ldw = 192; kbase = 0;   NT = 12; local = f - 72; }
  else if (f < 160) { src = Wv; ldw = 64;  kbase = 0;   NT = 4;  local = f - 144; }
  else if (f < 168) { src = Wv; ldw = 64;  kbase = 128; NT = 4;  local = f - 160; }
  else              { src = Wv; ldw = 64;  kbase = 192; NT = 4;  local = f - 168; }
  int kb = local / NT, nt = local % NT;
  int k0  = kbase + kb * 32 + (lane >> 4) * 8;
  int col = nt * 16 + (lane & 15);
  ushort* o = dst + ((size_t)f * 64 + lane) * 8;
#pragma unroll
  for (int j = 0; j < 8; ++j) o[j] = f2b(src[(size_t)(k0 + j) * ldw + col]);
}

// ---------------- main fused kernel (barrier-free, wave-private arenas) ----------
__global__ __launch_bounds__(256, 2) void fctp_main(
    const float* __restrict__ node, const float* __restrict__ eattr,
    const float* __restrict__ es, const float* __restrict__ b1,
    const float* __restrict__ b2, const float* __restrict__ offs,
    const float* __restrict__ bs, const float* __restrict__ g_s,
    const float* __restrict__ b_n, const float* __restrict__ g_v,
    const short8* __restrict__ wsv, float* __restrict__ out, int E) {
  __shared__ __align__(16) char smem[WAVES * 8192];
  const int lane = threadIdx.x & 63, wave = threadIdx.x >> 6;
  const int l15 = lane & 15, lg = lane >> 4;
  const int ebW = (int)blockIdx.x * EPB + wave * EPW;
  if (ebW >= E) return;
  char* ar0 = smem + wave * 8192;
  char* ar1 = ar0 + 4096;

  int geA[2];
#pragma unroll
  for (int t = 0; t < 2; ++t) { int g = ebW + t * 16 + l15; geA[t] = (g < E) ? g : E - 1; }
  int geR[2][4];
  float e0v[2][4], e1v[2][4][3];
#pragma unroll
  for (int t = 0; t < 2; ++t)
#pragma unroll
    for (int r = 0; r < 4; ++r) {
      int g = ebW + t * 16 + lg * 4 + r; if (g >= E) g = E - 1;
      geR[t][r] = g;
      float4 ea = *(const float4*)(eattr + (size_t)g * 4);
      e0v[t][r] = ea.x; e1v[t][r][0] = ea.y; e1v[t][r][1] = ea.z; e1v[t][r][2] = ea.w;
    }

  // ---- stage 1: h1 = silu(es @ W1 + b1) -> ar0 ----
  {
    f32x4 acc[2][4];
#pragma unroll
    for (int nt = 0; nt < 4; ++nt) {
      float bv = b1[nt * 16 + l15];
#pragma unroll
      for (int t = 0; t < 2; ++t) acc[t][nt] = (f32x4){bv, bv, bv, bv};
    }
    short8 aes[2][2];
#pragma unroll
    for (int t = 0; t < 2; ++t)
#pragma unroll
      for (int kb = 0; kb < 2; ++kb) {
        const float* p = es + (size_t)geA[t] * 64 + kb * 32 + lg * 8;
        float4 xa = *(const float4*)p, xb = *(const float4*)(p + 4);
        short8 a;
        a[0] = (short)f2b(xa.x); a[1] = (short)f2b(xa.y); a[2] = (short)f2b(xa.z); a[3] = (short)f2b(xa.w);
        a[4] = (short)f2b(xb.x); a[5] = (short)f2b(xb.y); a[6] = (short)f2b(xb.z); a[7] = (short)f2b(xb.w);
        aes[t][kb] = a;
      }
#pragma unroll
    for (int kb = 0; kb < 2; ++kb)
#pragma unroll
      for (int nt = 0; nt < 4; ++nt) {
        short8 b = wsv[(F_W1 + kb * 4 + nt) * 64 + lane];
#pragma unroll
        for (int t = 0; t < 2; ++t) acc[t][nt] = MFMA(aes[t][kb], b, acc[t][nt]);
      }
#pragma unroll
    for (int t = 0; t < 2; ++t)
#pragma unroll
      for (int nt = 0; nt < 4; ++nt)
#pragma unroll
        for (int r = 0; r < 4; ++r)
          cw16(ar0, t * 16 + lg * 4 + r, nt * 16 + l15, f2b(fsilu(acc[t][nt][r])));
  }

  // ---- stage 2: h2 = silu(h1 @ W2 + b2) -> ar1 ----
  short8 ah[2][2];
  {
#pragma unroll
    for (int t = 0; t < 2; ++t) {
      ah[t][0] = cra(ar0, t * 16 + l15, 0, lg);
      ah[t][1] = cra(ar0, t * 16 + l15, 1, lg);
    }
    f32x4 acc[2][4];
#pragma unroll
    for (int nt = 0; nt < 4; ++nt) {
      float bv = b2[nt * 16 + l15];
#pragma unroll
      for (int t = 0; t < 2; ++t) acc[t][nt] = (f32x4){bv, bv, bv, bv};
    }
#pragma unroll
    for (int kb = 0; kb < 2; ++kb)
#pragma unroll
      for (int nt = 0; nt < 4; ++nt) {
        short8 b = wsv[(F_W2 + kb * 4 + nt) * 64 + lane];
#pragma unroll
        for (int t = 0; t < 2; ++t) acc[t][nt] = MFMA(ah[t][kb], b, acc[t][nt]);
      }
#pragma unroll
    for (int t = 0; t < 2; ++t)
#pragma unroll
      for (int nt = 0; nt < 4; ++nt)
#pragma unroll
        for (int r = 0; r < 4; ++r)
          cw16(ar1, t * 16 + lg * 4 + r, nt * 16 + l15, f2b(fsilu(acc[t][nt][r])));
  }
  // stage-3 A fragments (kept in regs for all 7 segments)
#pragma unroll
  for (int t = 0; t < 2; ++t) {
    ah[t][0] = cra(ar1, t * 16 + l15, 0, lg);
    ah[t][1] = cra(ar1, t * 16 + l15, 1, lg);
  }

  // ---- helpers ----
  auto wseg = [&](int seg, f32x4 (&w)[2][4]) {
#pragma unroll
    for (int nt = 0; nt < 4; ++nt) {
      float bv = offs[seg * 64 + nt * 16 + l15];
#pragma unroll
      for (int t = 0; t < 2; ++t) w[t][nt] = (f32x4){bv, bv, bv, bv};
    }
#pragma unroll
    for (int kb = 0; kb < 2; ++kb)
#pragma unroll
      for (int nt = 0; nt < 4; ++nt) {
        short8 b = wsv[(F_W3 + kb * 28 + seg * 4 + nt) * 64 + lane];
#pragma unroll
        for (int t = 0; t < 2; ++t) w[t][nt] = MFMA(ah[t][kb], b, w[t][nt]);
      }
  };
  auto gemm4 = [&](const char* a, int fb0, int fb1, f32x4 (&ac)[2][4]) {
    short8 av[2][2];
#pragma unroll
    for (int t = 0; t < 2; ++t) {
      av[t][0] = cra(a, t * 16 + l15, 0, lg);
      av[t][1] = cra(a, t * 16 + l15, 1, lg);
    }
#pragma unroll
    for (int nt = 0; nt < 4; ++nt) {
      short8 b = wsv[(fb0 + nt) * 64 + lane];
#pragma unroll
      for (int t = 0; t < 2; ++t) ac[t][nt] = MFMA(av[t][0], b, ac[t][nt]);
    }
#pragma unroll
    for (int nt = 0; nt < 4; ++nt) {
      short8 b = wsv[(fb1 + nt) * 64 + lane];
#pragma unroll
      for (int t = 0; t < 2; ++t) ac[t][nt] = MFMA(av[t][1], b, ac[t][nt]);
    }
  };
  auto gemm12 = [&](const char* a, int kb0, f32x4 (&sac)[2][12]) {
    short8 av[2][2];
#pragma unroll
    for (int t = 0; t < 2; ++t) {
      av[t][0] = cra(a, t * 16 + l15, 0, lg);
      av[t][1] = cra(a, t * 16 + l15, 1, lg);
    }
#pragma unroll
    for (int kb = 0; kb < 2; ++kb)
#pragma unroll
      for (int nt = 0; nt < 12; ++nt) {
        short8 b = wsv[(F_WS + (kb0 + kb) * 12 + nt) * 64 + lane];
#pragma unroll
        for (int t = 0; t < 2; ++t) sac[t][nt] = MFMA(av[t][kb], b, sac[t][nt]);
      }
  };
  auto tpS = [&](char* a, const f32x4 (&w)[2][4], int scol, bool mulE0) {
#pragma unroll
    for (int t = 0; t < 2; ++t)
#pragma unroll
      for (int r = 0; r < 4; ++r) {
        const float* ni = node + (size_t)geR[t][r] * kNodeW + scol;
#pragma unroll
        for (int nt = 0; nt < 4; ++nt) {
          float v = w[t][nt][r] * ni[nt * 16 + l15];
          if (mulE0) v *= e0v[t][r];
          cw16(a, t * 16 + lg * 4 + r, nt * 16 + l15, f2b(v));
        }
      }
  };
  auto tpD = [&](char* a, const f32x4 (&w)[2][4]) {
#pragma unroll
    for (int t = 0; t < 2; ++t)
#pragma unroll
      for (int r = 0; r < 4; ++r) {
        const float* ni = node + (size_t)geR[t][r] * kNodeW + 128;
#pragma unroll
        for (int nt = 0; nt < 4; ++nt) {
          int u = nt * 16 + l15;
          float dot = ni[3 * u] * e1v[t][r][0] + ni[3 * u + 1] * e1v[t][r][1] +
                      ni[3 * u + 2] * e1v[t][r][2];
          cw16(a, t * 16 + lg * 4 + r, u, f2b(w[t][nt][r] * dot * RS3));
        }
      }
  };
  auto tpQ = [&](char* a, const f32x4 (&w)[2][4], int c) {
#pragma unroll
    for (int t = 0; t < 2; ++t)
#pragma unroll
      for (int r = 0; r < 4; ++r) {
        const float* ni = node + (size_t)geR[t][r] * kNodeW + 128;
#pragma unroll
        for (int nt = 0; nt < 4; ++nt) {
          int u = nt * 16 + l15;
          cw16(a, t * 16 + lg * 4 + r, u, f2b(w[t][nt][r] * ni[3 * u + c]));
        }
      }
  };
  auto tpR = [&](char* a, const f32x4 (&w)[2][4], int c) {
    const int i1 = (c + 1) % 3, i2 = (c + 2) % 3;
#pragma unroll
    for (int t = 0; t < 2; ++t)
#pragma unroll
      for (int r = 0; r < 4; ++r) {
        const float* ni = node + (size_t)geR[t][r] * kNodeW + 128;
#pragma unroll
        for (int nt = 0; nt < 4; ++nt) {
          int u = nt * 16 + l15;
          float cr = ni[3 * u + i1] * e1v[t][r][i2] - ni[3 * u + i2] * e1v[t][r][i1];
          cw16(a, t * 16 + lg * 4 + r, u, f2b(w[t][nt][r] * cr * RS2));
        }
      }
  };

  // ---- stage 3 + fused partial-K GEMMs (chunk arenas ping-pong) ----
  f32x4 wacc[2][4], pacc[2][4];
#pragma unroll
  for (int t = 0; t < 2; ++t)
#pragma unroll
    for (int nt = 0; nt < 4; ++nt) pacc[t][nt] = (f32x4){0.f, 0.f, 0.f, 0.f};

  wseg(2, wacc); tpS(ar0, wacc, 0, false);  gemm4(ar0, F_WP,     F_WP + 4,  pacc);
  wseg(3, wacc); tpS(ar1, wacc, 64, false); gemm4(ar1, F_WP + 8, F_WP + 12, pacc);

  f32x4 sacc[2][12];
#pragma unroll
  for (int nt = 0; nt < 12; ++nt) {
    float bv = bs[nt * 16 + l15];
#pragma unroll
    for (int t = 0; t < 2; ++t) sacc[t][nt] = (f32x4){bv, bv, bv, bv};
  }
  wseg(0, wacc); tpS(ar0, wacc, 0, true);  gemm12(ar0, 0, sacc);
  wseg(1, wacc); tpS(ar1, wacc, 64, true); gemm12(ar1, 2, sacc);
  wseg(5, wacc); tpD(ar0, wacc);           gemm12(ar0, 4, sacc);

  // ---- layernorm + silu/gate ----
  float gate[2][4][4];
  {
    float gsv[12], bnv[12];
#pragma unroll
    for (int nt = 0; nt < 12; ++nt) { gsv[nt] = g_s[nt * 16 + l15]; bnv[nt] = b_n[nt * 16 + l15]; }
#pragma unroll
    for (int t = 0; t < 2; ++t)
#pragma unroll
      for (int r = 0; r < 4; ++r) {
        float sx = 0.f, sxx = 0.f;
#pragma unroll
        for (int nt = 0; nt < 12; ++nt) { float v = sacc[t][nt][r]; sx += v; sxx += v * v; }
#pragma unroll
        for (int m = 8; m >= 1; m >>= 1) { sx += __shfl_xor(sx, m); sxx += __shfl_xor(sxx, m); }
        float mean = sx * (1.0f / 192.0f);
        float var  = sxx * (1.0f / 192.0f) - mean * mean;
        float rstd = rsqrtf(var + 1e-5f);
        int geu = ebW + t * 16 + lg * 4 + r;
        bool valid = geu < E;
        float* ob = out + (size_t)(valid ? geu : 0) * kOutW;
#pragma unroll
        for (int nt = 0; nt < 12; ++nt) {
          float sn = gsv[nt] * (sacc[t][nt][r] - mean) * rstd + bnv[nt];
          if (nt < 8) { if (valid) ob[nt * 16 + l15] = fsilu(sn); }
          else gate[t][r][nt - 8] = fsig(sn);
        }
      }
  }

  // ---- v phase: vl[c] = pa*e1c + e0*qa_c, then += r GEMM ----
  f32x4 vl[3][2][4];
  wseg(4, wacc);
#pragma unroll
  for (int c = 0; c < 3; ++c) {
    char* a = (c & 1) ? ar1 : ar0;
    tpQ(a, wacc, c);
    f32x4 qacc[2][4];
#pragma unroll
    for (int t = 0; t < 2; ++t)
#pragma unroll
      for (int nt = 0; nt < 4; ++nt) qacc[t][nt] = (f32x4){0.f, 0.f, 0.f, 0.f};
    gemm4(a, F_WQ, F_WQ + 4, qacc);
#pragma unroll
    for (int t = 0; t < 2; ++t)
#pragma unroll
      for (int nt = 0; nt < 4; ++nt)
#pragma unroll
        for (int r = 0; r < 4; ++r)
          vl[c][t][nt][r] = pacc[t][nt][r] * e1v[t][r][c] + e0v[t][r] * qacc[t][nt][r];
  }
  wseg(6, wacc);
#pragma unroll
  for (int c = 0; c < 3; ++c) {
    char* a = (c & 1) ? ar1 : ar0;
    tpR(a, wacc, c);
    gemm4(a, F_WR, F_WR + 4, vl[c]);
  }

  // ---- v epilogue: RMS norm + gate + store ----
  {
    float gvv[4];
#pragma unroll
    for (int nt = 0; nt < 4; ++nt) gvv[nt] = g_v[nt * 16 + l15];
#pragma unroll
    for (int t = 0; t < 2; ++t)
#pragma unroll
      for (int r = 0; r < 4; ++r) {
        float vsq = 0.f;
#pragma unroll
        for (int c = 0; c < 3; ++c)
#pragma unroll
          for (int nt = 0; nt < 4; ++nt) { float v = vl[c][t][nt][r]; vsq += v * v; }
#pragma unroll
        for (int m = 8; m >= 1; m >>= 1) vsq += __shfl_xor(vsq, m);
        float vn = rsqrtf(vsq * (1.0f / 64.0f) + 1e-5f);
        int geu = ebW + t * 16 + lg * 4 + r;
        if (geu < E) {
          float* ob = out + (size_t)geu * kOutW + 128;
#pragma unroll
          for (int nt = 0; nt < 4; ++nt) {
            float m3 = gvv[nt] * vn * gate[t][r][nt];
            int o3 = (nt * 16 + l15) * 3;
            ob[o3 + 0] = m3 * vl[0][t][nt][r];
            ob[o3 + 1] = m3 * vl[1][t][nt][r];
            ob[o3 + 2] = m3 * vl[2][t][nt][r];
          }
        }
      }
  }
}

}  // namespace

extern "C" void kernel_launch(void* const* d_in, const int* in_sizes, int n_in,
                              void* d_out, int out_size, void* d_ws, size_t ws_size,
                              hipStream_t stream) {
  const float* node_input   = (const float*)d_in[0];
  const float* edge_attr    = (const float*)d_in[1];
  const float* edge_scalars = (const float*)d_in[2];
  const float* W1 = (const float*)d_in[3];
  const float* b1 = (const float*)d_in[4];
  const float* W2 = (const float*)d_in[5];
  const float* b2 = (const float*)d_in[6];
  const float* W3 = (const float*)d_in[7];
  const float* offset = (const float*)d_in[8];
  const float* Ws = (const float*)d_in[9];
  const float* bs = (const float*)d_in[10];
  const float* Wv = (const float*)d_in[11];
  const float* g_s = (const float*)d_in[12];
  const float* b_n = (const float*)d_in[13];
  const float* g_v = (const float*)d_in[14];
  float* out = (float*)d_out;

  const int E = in_sizes[0] / kNodeW;

  pack_weights<<<NFRAG, 64, 0, stream>>>(W1, W2, W3, Ws, Wv, (ushort*)d_ws);

  const int blocks = (E + EPB - 1) / EPB;
  fctp_main<<<blocks, WAVES * 64, 0, stream>>>(
      node_input, edge_attr, edge_scalars, b1, b2, offset, bs, g_s, b_n, g_v,
      (const short8*)d_ws, out, E);
}

// Round 4
// 344.628 us; speedup vs baseline: 1.7719x; 1.1634x over previous
//
#include <hip/hip_runtime.h>

typedef short short8 __attribute__((ext_vector_type(8)));
typedef __bf16 bf16x8 __attribute__((ext_vector_type(8)));
typedef float f32x4 __attribute__((ext_vector_type(4)));

namespace {

constexpr int kNodeW = 320;   // NS + 3*NV
constexpr int kOutW  = 320;   // NS + 3*VOUT

// wsv frag indices (packed by pack_weights); 1 frag = 64 lanes * 16 B = 1 KB
constexpr int F_W1 = 0;    // kb*4 + nt (kb<2)
constexpr int F_W2 = 8;
constexpr int F_W3 = 16;   // kb*28 + seg*4 + nt (kb<2, seg<7)
constexpr int F_WS = 72;   // kb*12 + nt (kb<6)
constexpr int F_WP = 144;  // kb*4 + nt (kb<4)   Wv rows 0..127
constexpr int F_WQ = 160;  // kb*4 + nt (kb<2)   Wv rows 128..191
constexpr int F_WR = 168;  // kb*4 + nt (kb<2)   Wv rows 192..255
constexpr int NFRAG = 176;

// LDS: [0,56K) W3 frags, [56K,128K) Ws frags, [128K,144K) 8 x 2KB wave arenas
constexpr int L_W3 = 0;
constexpr int L_WS = 56;
constexpr int ARENA_OFF = 128 * 1024;
constexpr int SMEM_SZ = 144 * 1024;

constexpr float RS3 = 0.5773502691896258f;  // 1/sqrt(3)
constexpr float RS2 = 0.7071067811865476f;  // 1/sqrt(2)

__device__ __forceinline__ ushort f2b(float f) {
  uint x = __float_as_uint(f);
  return (ushort)((x + 0x7FFFu + ((x >> 16) & 1u)) >> 16);  // RNE
}
__device__ __forceinline__ float fsig(float x) { return 1.0f / (1.0f + __expf(-x)); }
__device__ __forceinline__ float fsilu(float x) { return x / (1.0f + __expf(-x)); }
__device__ __forceinline__ f32x4 MFMA(short8 a, short8 b, f32x4 c) {
  return __builtin_amdgcn_mfma_f32_16x16x32_bf16(
      __builtin_bit_cast(bf16x8, a), __builtin_bit_cast(bf16x8, b), c, 0, 0, 0);
}

// wave-private arena: 16 rows x 64 bf16 (128 B rows), XOR swizzle on the row stride
__device__ __forceinline__ void cw16(char* ar, int row, int col, ushort v) {
  *(ushort*)(ar + ((row * 128 + col * 2) ^ ((row & 7) << 4))) = v;
}
__device__ __forceinline__ short8 cra(const char* ar, int row, int kb, int lg) {
  return *(const short8*)(ar + ((row * 128 + kb * 64 + lg * 16) ^ ((row & 7) << 4)));
}

// ---------------- B pack: f32 [K][N] -> bf16 frag layout in d_ws ----------------
__global__ void pack_weights(const float* __restrict__ W1, const float* __restrict__ W2,
                             const float* __restrict__ W3, const float* __restrict__ Ws,
                             const float* __restrict__ Wv, ushort* __restrict__ dst) {
  int f = blockIdx.x, lane = threadIdx.x;
  const float* src; int ldw, kbase, NT, local;
  if (f < 8)        { src = W1; ldw = 64;  kbase = 0;   NT = 4;  local = f; }
  else if (f < 16)  { src = W2; ldw = 64;  kbase = 0;   NT = 4;  local = f - 8; }
  else if (f < 72)  { src = W3; ldw = 448; kbase = 0;   NT = 28; local = f - 16; }
  else if (f < 144) { src = Ws; ldw = 192; kbase = 0;   NT = 12; local = f - 72; }
  else if (f < 160) { src = Wv; ldw = 64;  kbase = 0;   NT = 4;  local = f - 144; }
  else if (f < 168) { src = Wv; ldw = 64;  kbase = 128; NT = 4;  local = f - 160; }
  else              { src = Wv; ldw = 64;  kbase = 192; NT = 4;  local = f - 168; }
  int kb = local / NT, nt = local % NT;
  int k0  = kbase + kb * 32 + (lane >> 4) * 8;
  int col = nt * 16 + (lane & 15);
  ushort* o = dst + ((size_t)f * 64 + lane) * 8;
#pragma unroll
  for (int j = 0; j < 8; ++j) o[j] = f2b(src[(size_t)(k0 + j) * ldw + col]);
}

// ---------------- main fused kernel: weight-stationary, 8 waves/block ----------
__global__ __launch_bounds__(512, 2) void fctp_main(
    const float* __restrict__ node, const float* __restrict__ eattr,
    const float* __restrict__ es, const float* __restrict__ b1,
    const float* __restrict__ b2, const float* __restrict__ offs,
    const float* __restrict__ bs, const float* __restrict__ g_s,
    const float* __restrict__ b_n, const float* __restrict__ g_v,
    const short8* __restrict__ wsv, float* __restrict__ out, int E) {
  __shared__ __align__(16) char smem[SMEM_SZ];
  const int lane = threadIdx.x & 63, wave = threadIdx.x >> 6;
  const int l15 = lane & 15, lg = lane >> 4;

  // ---- one-time: stage W3 + Ws fragments into LDS (16 frags per wave) ----
#pragma unroll
  for (int i = 0; i < 16; ++i) {
    int fl = wave * 16 + i;
    int fg = (fl < 56) ? (F_W3 + fl) : (F_WS + (fl - 56));
    *(short8*)(smem + fl * 1024 + lane * 16) = wsv[fg * 64 + lane];
  }
  __syncthreads();

  char* ar = smem + ARENA_OFF + wave * 2048;
  auto ldsB = [&](int f) -> short8 {
    return *(const short8*)(smem + f * 1024 + lane * 16);
  };

  const int ntiles = (E + 15) >> 4;
  for (int tile = (int)blockIdx.x * 8 + wave; tile < ntiles; tile += (int)gridDim.x * 8) {
    const int e0 = tile * 16;
    int geA = e0 + l15; if (geA >= E) geA = E - 1;
    int geR[4];
    float e0v[4], e1v[4][3];
#pragma unroll
    for (int r = 0; r < 4; ++r) {
      int g = e0 + lg * 4 + r; if (g >= E) g = E - 1;
      geR[r] = g;
      float4 ea = *(const float4*)(eattr + (size_t)g * 4);
      e0v[r] = ea.x; e1v[r][0] = ea.y; e1v[r][1] = ea.z; e1v[r][2] = ea.w;
    }

    // node preloads (single pass; lane's C-layout rows)
    float sn[4][8];
    float vn[4][4][3];
#pragma unroll
    for (int r = 0; r < 4; ++r) {
      const float* ni = node + (size_t)geR[r] * kNodeW;
#pragma unroll
      for (int nt = 0; nt < 8; ++nt) sn[r][nt] = ni[nt * 16 + l15];
#pragma unroll
      for (int nt = 0; nt < 4; ++nt) {
        const float* vp = ni + 128 + 3 * (nt * 16 + l15);
        vn[r][nt][0] = vp[0]; vn[r][nt][1] = vp[1]; vn[r][nt][2] = vp[2];
      }
    }

    // es A-fragments
    short8 aes[2];
#pragma unroll
    for (int kb = 0; kb < 2; ++kb) {
      const float* p = es + (size_t)geA * 64 + kb * 32 + lg * 8;
      float4 xa = *(const float4*)p, xb = *(const float4*)(p + 4);
      short8 a;
      a[0] = (short)f2b(xa.x); a[1] = (short)f2b(xa.y); a[2] = (short)f2b(xa.z); a[3] = (short)f2b(xa.w);
      a[4] = (short)f2b(xb.x); a[5] = (short)f2b(xb.y); a[6] = (short)f2b(xb.z); a[7] = (short)f2b(xb.w);
      aes[kb] = a;
    }

    // ---- MLP stage 1 ----
    short8 ah[2];
    {
      f32x4 acc[4];
#pragma unroll
      for (int nt = 0; nt < 4; ++nt) { float bv = b1[nt * 16 + l15]; acc[nt] = (f32x4){bv, bv, bv, bv}; }
#pragma unroll
      for (int kb = 0; kb < 2; ++kb)
#pragma unroll
        for (int nt = 0; nt < 4; ++nt)
          acc[nt] = MFMA(aes[kb], wsv[(F_W1 + kb * 4 + nt) * 64 + lane], acc[nt]);
#pragma unroll
      for (int nt = 0; nt < 4; ++nt)
#pragma unroll
        for (int r = 0; r < 4; ++r)
          cw16(ar, lg * 4 + r, nt * 16 + l15, f2b(fsilu(acc[nt][r])));
      ah[0] = cra(ar, l15, 0, lg);
      ah[1] = cra(ar, l15, 1, lg);
    }
    // ---- MLP stage 2 ----
    {
      f32x4 acc[4];
#pragma unroll
      for (int nt = 0; nt < 4; ++nt) { float bv = b2[nt * 16 + l15]; acc[nt] = (f32x4){bv, bv, bv, bv}; }
#pragma unroll
      for (int kb = 0; kb < 2; ++kb)
#pragma unroll
        for (int nt = 0; nt < 4; ++nt)
          acc[nt] = MFMA(ah[kb], wsv[(F_W2 + kb * 4 + nt) * 64 + lane], acc[nt]);
#pragma unroll
      for (int nt = 0; nt < 4; ++nt)
#pragma unroll
        for (int r = 0; r < 4; ++r)
          cw16(ar, lg * 4 + r, nt * 16 + l15, f2b(fsilu(acc[nt][r])));
      ah[0] = cra(ar, l15, 0, lg);
      ah[1] = cra(ar, l15, 1, lg);
    }

    // ---- helpers ----
    auto wseg = [&](int seg, f32x4 (&w)[4]) {
#pragma unroll
      for (int nt = 0; nt < 4; ++nt) {
        float bv = offs[seg * 64 + nt * 16 + l15];
        w[nt] = (f32x4){bv, bv, bv, bv};
      }
#pragma unroll
      for (int kb = 0; kb < 2; ++kb)
#pragma unroll
        for (int nt = 0; nt < 4; ++nt)
          w[nt] = MFMA(ah[kb], ldsB(L_W3 + kb * 28 + seg * 4 + nt), w[nt]);
    };
    auto gemm12 = [&](int kb0, f32x4 (&sac)[12]) {
      short8 a0 = cra(ar, l15, 0, lg), a1 = cra(ar, l15, 1, lg);
#pragma unroll
      for (int nt = 0; nt < 12; ++nt) sac[nt] = MFMA(a0, ldsB(L_WS + kb0 * 12 + nt), sac[nt]);
#pragma unroll
      for (int nt = 0; nt < 12; ++nt) sac[nt] = MFMA(a1, ldsB(L_WS + (kb0 + 1) * 12 + nt), sac[nt]);
    };
    auto gemm4 = [&](int fb0, int fb1, f32x4 (&ac)[4]) {
      short8 a0 = cra(ar, l15, 0, lg), a1 = cra(ar, l15, 1, lg);
#pragma unroll
      for (int nt = 0; nt < 4; ++nt) ac[nt] = MFMA(a0, wsv[(fb0 + nt) * 64 + lane], ac[nt]);
#pragma unroll
      for (int nt = 0; nt < 4; ++nt) ac[nt] = MFMA(a1, wsv[(fb1 + nt) * 64 + lane], ac[nt]);
    };
    auto tpS = [&](const f32x4 (&w)[4], int nb, bool mulE0) {
#pragma unroll
      for (int nt = 0; nt < 4; ++nt)
#pragma unroll
        for (int r = 0; r < 4; ++r) {
          float v = w[nt][r] * sn[r][nb + nt];
          if (mulE0) v *= e0v[r];
          cw16(ar, lg * 4 + r, nt * 16 + l15, f2b(v));
        }
    };
    auto tpD = [&](const f32x4 (&w)[4]) {
#pragma unroll
      for (int nt = 0; nt < 4; ++nt)
#pragma unroll
        for (int r = 0; r < 4; ++r) {
          float dot = vn[r][nt][0] * e1v[r][0] + vn[r][nt][1] * e1v[r][1] +
                      vn[r][nt][2] * e1v[r][2];
          cw16(ar, lg * 4 + r, nt * 16 + l15, f2b(w[nt][r] * dot * RS3));
        }
    };
    auto tpQ = [&](const f32x4 (&w)[4], int c) {
#pragma unroll
      for (int nt = 0; nt < 4; ++nt)
#pragma unroll
        for (int r = 0; r < 4; ++r)
          cw16(ar, lg * 4 + r, nt * 16 + l15, f2b(w[nt][r] * vn[r][nt][c]));
    };
    auto tpR = [&](const f32x4 (&w)[4], int c) {
      const int i1 = (c + 1) % 3, i2 = (c + 2) % 3;
#pragma unroll
      for (int nt = 0; nt < 4; ++nt)
#pragma unroll
        for (int r = 0; r < 4; ++r) {
          float cr = vn[r][nt][i1] * e1v[r][i2] - vn[r][nt][i2] * e1v[r][i1];
          cw16(ar, lg * 4 + r, nt * 16 + l15, f2b(w[nt][r] * cr * RS2));
        }
    };

    // ---- s phase: sacc = scal @ Ws + bs (partial-K through arena) ----
    f32x4 wacc[4];
    f32x4 sacc[12];
#pragma unroll
    for (int nt = 0; nt < 12; ++nt) { float bv = bs[nt * 16 + l15]; sacc[nt] = (f32x4){bv, bv, bv, bv}; }
    wseg(0, wacc); tpS(wacc, 0, true);  gemm12(0, sacc);
    wseg(1, wacc); tpS(wacc, 4, true);  gemm12(2, sacc);
    wseg(5, wacc); tpD(wacc);           gemm12(4, sacc);

    // ---- layernorm + silu / gate + scalar store ----
    float gate[4][4];
    {
      float gsv[12], bnv[12];
#pragma unroll
      for (int nt = 0; nt < 12; ++nt) { gsv[nt] = g_s[nt * 16 + l15]; bnv[nt] = b_n[nt * 16 + l15]; }
#pragma unroll
      for (int r = 0; r < 4; ++r) {
        float sx = 0.f, sxx = 0.f;
#pragma unroll
        for (int nt = 0; nt < 12; ++nt) { float v = sacc[nt][r]; sx += v; sxx += v * v; }
#pragma unroll
        for (int m = 8; m >= 1; m >>= 1) { sx += __shfl_xor(sx, m); sxx += __shfl_xor(sxx, m); }
        float mean = sx * (1.0f / 192.0f);
        float var  = sxx * (1.0f / 192.0f) - mean * mean;
        float rstd = rsqrtf(var + 1e-5f);
        int geu = e0 + lg * 4 + r;
        bool valid = geu < E;
        float* ob = out + (size_t)(valid ? geu : 0) * kOutW;
#pragma unroll
        for (int nt = 0; nt < 12; ++nt) {
          float s_n = gsv[nt] * (sacc[nt][r] - mean) * rstd + bnv[nt];
          if (nt < 8) { if (valid) ob[nt * 16 + l15] = fsilu(s_n); }
          else gate[r][nt - 8] = fsig(s_n);
        }
      }
    }

    // ---- v phase ----
    f32x4 pacc[4];
#pragma unroll
    for (int nt = 0; nt < 4; ++nt) pacc[nt] = (f32x4){0.f, 0.f, 0.f, 0.f};
    wseg(2, wacc); tpS(wacc, 0, false); gemm4(F_WP,     F_WP + 4,  pacc);
    wseg(3, wacc); tpS(wacc, 4, false); gemm4(F_WP + 8, F_WP + 12, pacc);

    f32x4 vl[3][4];
    wseg(4, wacc);
#pragma unroll
    for (int c = 0; c < 3; ++c) {
      tpQ(wacc, c);
      f32x4 q[4];
#pragma unroll
      for (int nt = 0; nt < 4; ++nt) q[nt] = (f32x4){0.f, 0.f, 0.f, 0.f};
      gemm4(F_WQ, F_WQ + 4, q);
#pragma unroll
      for (int nt = 0; nt < 4; ++nt)
#pragma unroll
        for (int r = 0; r < 4; ++r)
          vl[c][nt][r] = pacc[nt][r] * e1v[r][c] + e0v[r] * q[nt][r];
    }
    wseg(6, wacc);
#pragma unroll
    for (int c = 0; c < 3; ++c) {
      tpR(wacc, c);
      gemm4(F_WR, F_WR + 4, vl[c]);
    }

    // ---- RMS norm + gate + vector store ----
    {
      float gvv[4];
#pragma unroll
      for (int nt = 0; nt < 4; ++nt) gvv[nt] = g_v[nt * 16 + l15];
#pragma unroll
      for (int r = 0; r < 4; ++r) {
        float vsq = 0.f;
#pragma unroll
        for (int c = 0; c < 3; ++c)
#pragma unroll
          for (int nt = 0; nt < 4; ++nt) { float v = vl[c][nt][r]; vsq += v * v; }
#pragma unroll
        for (int m = 8; m >= 1; m >>= 1) vsq += __shfl_xor(vsq, m);
        float vnrm = rsqrtf(vsq * (1.0f / 64.0f) + 1e-5f);
        int geu = e0 + lg * 4 + r;
        if (geu < E) {
          float* ob = out + (size_t)geu * kOutW + 128;
#pragma unroll
          for (int nt = 0; nt < 4; ++nt) {
            float m3 = gvv[nt] * vnrm * gate[r][nt];
            int o3 = (nt * 16 + l15) * 3;
            ob[o3 + 0] = m3 * vl[0][nt][r];
            ob[o3 + 1] = m3 * vl[1][nt][r];
            ob[o3 + 2] = m3 * vl[2][nt][r];
          }
        }
      }
    }
  }
}

}  // namespace

extern "C" void kernel_launch(void* const* d_in, const int* in_sizes, int n_in,
                              void* d_out, int out_size, void* d_ws, size_t ws_size,
                              hipStream_t stream) {
  const float* node_input   = (const float*)d_in[0];
  const float* edge_attr    = (const float*)d_in[1];
  const float* edge_scalars = (const float*)d_in[2];
  const float* W1 = (const float*)d_in[3];
  const float* b1 = (const float*)d_in[4];
  const float* W2 = (const float*)d_in[5];
  const float* b2 = (const float*)d_in[6];
  const float* W3 = (const float*)d_in[7];
  const float* offset = (const float*)d_in[8];
  const float* Ws = (const float*)d_in[9];
  const float* bs = (const float*)d_in[10];
  const float* Wv = (const float*)d_in[11];
  const float* g_s = (const float*)d_in[12];
  const float* b_n = (const float*)d_in[13];
  const float* g_v = (const float*)d_in[14];
  float* out = (float*)d_out;

  const int E = in_sizes[0] / kNodeW;

  pack_weights<<<NFRAG, 64, 0, stream>>>(W1, W2, W3, Ws, Wv, (ushort*)d_ws);

  const int ntiles = (E + 15) / 16;
  int blocks = (ntiles + 7) / 8;
  if (blocks > 256) blocks = 256;
  fctp_main<<<blocks, 512, 0, stream>>>(
      node_input, edge_attr, edge_scalars, b1, b2, offset, bs, g_s, b_n, g_v,
      (const short8*)d_ws, out, E);
}